// Round 2
// baseline (486.314 us; speedup 1.0000x reference)
//
#include <hip/hip_runtime.h>
#include <hip/hip_bf16.h>
#include <stdint.h>

#define BB 4
#define SS 2048
#define DD 1024
#define HH 16
#define DKK 64
#define MT (BB*SS)   // 8192
#define KK DD        // 1024

typedef __attribute__((ext_vector_type(8))) short bf16x8;
typedef __attribute__((ext_vector_type(4))) short s16x4;
typedef __attribute__((ext_vector_type(4))) float f32x4;
typedef __attribute__((ext_vector_type(8))) unsigned short u16x8;

__device__ __forceinline__ unsigned short f2bf(float f){
  union { float f; unsigned u; } x; x.f = f;
  unsigned r = x.u + 0x7fffu + ((x.u >> 16) & 1u);   // RNE
  return (unsigned short)(r >> 16);
}

__device__ __forceinline__ void gll16(const void* g, void* l){
  __builtin_amdgcn_global_load_lds(
      (const __attribute__((address_space(1))) void*)g,
      (__attribute__((address_space(3))) void*)l, 16, 0, 0);
}

// ---------------- fp32 -> bf16 convert (8 elems/thread) ----------------
__global__ __launch_bounds__(256) void cvt_bf16(const float* __restrict__ in,
                                                unsigned short* __restrict__ out){
  int i = blockIdx.x * 256 + threadIdx.x;
  const f32x4* p = (const f32x4*)in;
  f32x4 a = p[2*i], b = p[2*i+1];
  u16x8 o;
  #pragma unroll
  for (int j=0;j<4;j++){ o[j] = f2bf(a[j]); o[4+j] = f2bf(b[j]); }
  ((u16x8*)out)[i] = o;
}

// ---------------- weights: transpose to [N][K] bf16, fuse fc_w*Wq ----------------
__global__ __launch_bounds__(256) void prep_weights(
    const float* __restrict__ fc, const float* __restrict__ Wq,
    const float* __restrict__ Wk, const float* __restrict__ Wv,
    const float* __restrict__ Wo,
    unsigned short* __restrict__ Wqt, unsigned short* __restrict__ Wkt,
    unsigned short* __restrict__ Wvt, unsigned short* __restrict__ Wot){
  __shared__ float tile[32][33];
  int which = blockIdx.y;
  const float* src = which==0?Wq: which==1?Wk: which==2?Wv:Wo;
  unsigned short* dst = which==0?Wqt: which==1?Wkt: which==2?Wvt:Wot;
  int k0 = (blockIdx.x & 31)*32, n0 = (blockIdx.x >> 5)*32;
  int tid = threadIdx.x;
  #pragma unroll
  for (int i=0;i<4;i++){
    int e = tid + i*256; int r = e>>5, c = e&31;
    float v = src[(size_t)(k0+r)*DD + n0 + c];
    if (which==0) v *= fc[(size_t)(k0+r)*DD + n0 + c];
    tile[r][c] = v;
  }
  __syncthreads();
  #pragma unroll
  for (int i=0;i<4;i++){
    int e = tid + i*256; int r = e>>5, c = e&31;
    dst[(size_t)(n0+r)*DD + k0 + c] = f2bf(tile[c][r]);
  }
}

// ---------------- GEMM: C[M][N] = A[M][K](bf16) @ Bt[N][K]^T (bf16) + bias ----------------
// EPI=0: write bf16 in [B,H,S,DK] head layout.  EPI=1: write fp32 [M][N].
template<int EPI>
__global__ __launch_bounds__(256) void gemm_bt(
    const unsigned short* __restrict__ A,
    const unsigned short* __restrict__ Bt,
    const float* __restrict__ bias,
    void* __restrict__ Cout){
  __shared__ __align__(16) unsigned short Asb[2][128*32];
  __shared__ __align__(16) unsigned short Bsb[2][128*32];
  const int tid = threadIdx.x;
  const int lane = tid & 63, wid = tid >> 6;
  const int m0 = blockIdx.y * 128, n0 = blockIdx.x * 128;
  const int wm = wid >> 1, wn = wid & 1;
  const int g = lane >> 4, lr = lane & 15;

  f32x4 acc[4][4];
  #pragma unroll
  for (int i=0;i<4;i++)
    #pragma unroll
    for (int j=0;j<4;j++) acc[i][j] = (f32x4){0.f,0.f,0.f,0.f};

  const char* gaBase = (const char*)(A  + (size_t)m0 * KK);
  const char* gbBase = (const char*)(Bt + (size_t)n0 * KK);

  auto stage = [&](int buf, int kt){
    #pragma unroll
    for (int is=0; is<2; ++is){
      int t = is*4096 + wid*1024 + lane*16;   // tile byte (linear)
      int row = t >> 6, col = t & 63;         // 64B rows (BK=32 bf16)
      gll16(gaBase + (size_t)row*(KK*2) + (size_t)kt*64 + col,
            (char*)&Asb[buf][0] + is*4096 + wid*1024);
      gll16(gbBase + (size_t)row*(KK*2) + (size_t)kt*64 + col,
            (char*)&Bsb[buf][0] + is*4096 + wid*1024);
    }
  };

  stage(0, 0);
  __syncthreads();
  int cur = 0;
  for (int kt = 0; kt < KK/32; ++kt){
    if (kt + 1 < KK/32) stage(cur^1, kt+1);
    bf16x8 af[4], bfr[4];
    #pragma unroll
    for (int f=0; f<4; ++f){
      int ar = wm*64 + f*16 + lr;
      af[f]  = *(const bf16x8*)&Asb[cur][ar*32 + g*8];
      int br = wn*64 + f*16 + lr;
      bfr[f] = *(const bf16x8*)&Bsb[cur][br*32 + g*8];
    }
    #pragma unroll
    for (int i=0;i<4;i++)
      #pragma unroll
      for (int j=0;j<4;j++)
        acc[i][j] = __builtin_amdgcn_mfma_f32_16x16x32_bf16(af[i], bfr[j], acc[i][j], 0, 0, 0);
    __syncthreads();
    cur ^= 1;
  }

  #pragma unroll
  for (int j=0;j<4;j++){
    int n = n0 + wn*64 + j*16 + lr;
    float bv = bias[n];
    #pragma unroll
    for (int i=0;i<4;i++){
      int mbase = m0 + wm*64 + i*16 + g*4;
      #pragma unroll
      for (int r=0;r<4;r++){
        int m = mbase + r;
        float v = acc[i][j][r] + bv;
        if (EPI == 0){
          int b = m >> 11, s = m & (SS-1);
          int h = n >> 6, dk = n & 63;
          ((unsigned short*)Cout)[(((size_t)(b*HH + h))*SS + s)*DKK + dk] = f2bf(v);
        } else {
          ((float*)Cout)[(size_t)m*DD + n] = v;
        }
      }
    }
  }
}

// ---------------- V [BH][S][64] -> Vt [BH][64][S] ----------------
__global__ __launch_bounds__(256) void transpose_v(const unsigned short* __restrict__ V,
                                                   unsigned short* __restrict__ Vt){
  __shared__ unsigned short t[64][72];
  int bh = blockIdx.y; int s0 = blockIdx.x*64;
  const unsigned short* src = V + ((size_t)bh*SS + s0)*DKK;
  int tid = threadIdx.x;
  #pragma unroll
  for (int i=0;i<2;i++){
    int e = (tid + i*256)*8; int r = e>>6, c = e&63;
    u16x8 v = *(const u16x8*)(src + (size_t)r*DKK + c);
    #pragma unroll
    for (int j=0;j<8;j++) t[c+j][r] = v[j];
  }
  __syncthreads();
  unsigned short* dst = Vt + ((size_t)bh*DKK)*SS + s0;
  #pragma unroll
  for (int i=0;i<2;i++){
    int e = (tid + i*256)*8; int d = e>>6, c = e&63;
    u16x8 v = *(const u16x8*)(&t[d][c]);
    *(u16x8*)(dst + (size_t)d*SS + c) = v;
  }
}

// ---------------- flash attention ----------------
// Q,K: [BH][S][64] bf16; Vt: [BH][64][S] bf16; X out: [B][S][D] bf16.
// 64 q-rows/block, 4 waves x 16 q-rows; KV tiles of 64, double-buffered.
// Swapped QK^T (mfma(K,Q)) -> per-lane P rows; LDS rows (128B) XOR-swizzled at the
// global SOURCE of global_load_lds (linear dest) and at ds_read (rule 21).
__global__ __launch_bounds__(256) void attn(
    const unsigned short* __restrict__ Qg,
    const unsigned short* __restrict__ Kg,
    const unsigned short* __restrict__ Vtg,
    unsigned short* __restrict__ Xg){
  __shared__ __align__(16) unsigned short Qs[64*64];
  __shared__ __align__(16) unsigned short Ks[2][64*64];
  __shared__ __align__(16) unsigned short Vs[2][64*64];
  const int tid = threadIdx.x;
  const int lane = tid & 63, wid = tid >> 6;
  const int g = lane >> 4, lr = lane & 15;
  const int bh = blockIdx.y;
  const int q0 = blockIdx.x * 64;

  const char* Qbase = (const char*)(Qg + ((size_t)bh*SS + q0)*DKK);
  const char* Kbase = (const char*)(Kg + (size_t)bh*SS*DKK);
  const char* Vbase = (const char*)(Vtg + (size_t)bh*DKK*SS);

  // ---- stage Q (8KB contiguous), source-swizzled ----
  #pragma unroll
  for (int is=0; is<2; ++is){
    int t = is*4096 + wid*1024 + lane*16;
    int row = t >> 7;
    int col = (t & 127) ^ ((row & 7) << 4);
    gll16(Qbase + row*128 + col, (char*)Qs + is*4096 + wid*1024);
  }

  auto stageK = [&](int buf, int it){
    const char* gk = Kbase + (size_t)it*8192;      // contiguous 64x128B tile
    #pragma unroll
    for (int is=0; is<2; ++is){
      int t = is*4096 + wid*1024 + lane*16;
      int row = t >> 7;
      int col = (t & 127) ^ ((row & 7) << 4);
      gll16(gk + row*128 + col, (char*)&Ks[buf][0] + is*4096 + wid*1024);
    }
  };
  auto stageV = [&](int buf, int it){
    #pragma unroll
    for (int is=0; is<2; ++is){
      int t = is*4096 + wid*1024 + lane*16;
      int row = t >> 7;                             // dk row, global stride S*2
      int col = (t & 127) ^ ((row & 7) << 4);
      gll16(Vbase + (size_t)row*(SS*2) + (size_t)it*128 + col,
            (char*)&Vs[buf][0] + is*4096 + wid*1024);
    }
  };

  stageK(0, 0); stageV(0, 0);
  __syncthreads();

  // Q fragments, register-resident for the whole block
  bf16x8 qf[2];
  {
    int qrow = wid*16 + lr;
    int sw = (qrow & 7) << 4;
    #pragma unroll
    for (int h2=0; h2<2; ++h2){
      int cb = (g*8 + h2*32) * 2;
      qf[h2] = *(const bf16x8*)((const char*)Qs + qrow*128 + (cb ^ sw));
    }
  }

  f32x4 Xf[4];
  #pragma unroll
  for (int d=0; d<4; ++d) Xf[d] = (f32x4){0.f,0.f,0.f,0.f};
  float m2 = -1e30f, ell = 0.f;
  const float SC2 = 0.18033688011112042f;   // (1/sqrt(64)) * log2(e)

  int cur = 0;
  for (int it = 0; it < SS/64; ++it){
    if (it + 1 < SS/64){ stageK(cur^1, it+1); stageV(cur^1, it+1); }

    // ---- S^T = K @ Q^T : lane holds S[kv = s*16 + g*4 + r][q = lr] ----
    f32x4 st[4];
    #pragma unroll
    for (int s=0; s<4; ++s){
      st[s] = (f32x4){0.f,0.f,0.f,0.f};
      int krow = s*16 + lr;
      int rb = krow*128, sw = (krow & 7) << 4;
      #pragma unroll
      for (int h2=0; h2<2; ++h2){
        bf16x8 kf = *(const bf16x8*)((const char*)&Ks[cur][0] + rb + ((((g*8 + h2*32))*2) ^ sw));
        st[s] = __builtin_amdgcn_mfma_f32_16x16x32_bf16(kf, qf[h2], st[s], 0, 0, 0);
      }
    }

    // ---- online softmax (log2 domain), per-lane q = lr ----
    float z[4][4];
    float tmax = -1e30f;
    #pragma unroll
    for (int s=0; s<4; ++s)
      #pragma unroll
      for (int r=0; r<4; ++r){ z[s][r] = st[s][r] * SC2; tmax = fmaxf(tmax, z[s][r]); }
    tmax = fmaxf(tmax, __shfl_xor(tmax, 16));
    tmax = fmaxf(tmax, __shfl_xor(tmax, 32));
    float mn = fmaxf(m2, tmax);
    float sc = exp2f(m2 - mn);
    m2 = mn;
    float p[4][4]; float ps = 0.f;
    #pragma unroll
    for (int s=0; s<4; ++s)
      #pragma unroll
      for (int r=0; r<4; ++r){ p[s][r] = exp2f(z[s][r] - mn); ps += p[s][r]; }
    ps += __shfl_xor(ps, 16);
    ps += __shfl_xor(ps, 32);
    ell = ell * sc + ps;
    // rescale accumulator: X row q = g*4+r needs sc from lane (g*4+r)
    #pragma unroll
    for (int r=0; r<4; ++r){
      float scr = __shfl(sc, g*4 + r);
      #pragma unroll
      for (int d=0; d<4; ++d) Xf[d][r] *= scr;
    }

    // ---- P -> bf16 A-fragments (k-slot map f(g,j) = g*4 + (j&3) + 16*(j>>2)) ----
    bf16x8 pa0, pa1;
    #pragma unroll
    for (int j=0; j<8; ++j){
      pa0[j] = (short)f2bf(p[(j>>2)    ][j&3]);
      pa1[j] = (short)f2bf(p[2 + (j>>2)][j&3]);
    }

    // ---- X += P @ V  (B from Vt LDS with the SAME k-slot map) ----
    #pragma unroll
    for (int d=0; d<4; ++d){
      int vrow = d*16 + lr;
      int rb = vrow*128, sw = (vrow & 7) << 4;
      #pragma unroll
      for (int mh=0; mh<2; ++mh){
        int c0 = 64*mh + g*8;                      // byte col of kv = mh*32 + g*4
        s16x4 lo = *(const s16x4*)((const char*)&Vs[cur][0] + rb + (c0 ^ sw));
        s16x4 hi = *(const s16x4*)((const char*)&Vs[cur][0] + rb + ((c0 + 32) ^ sw));
        bf16x8 bv = __builtin_shufflevector(lo, hi, 0,1,2,3,4,5,6,7);
        Xf[d] = __builtin_amdgcn_mfma_f32_16x16x32_bf16(mh ? pa1 : pa0, bv, Xf[d], 0, 0, 0);
      }
    }
    __syncthreads();
    cur ^= 1;
  }

  // ---- finalize: divide by ell of row q = g*4+r, write [B,S,D] bf16 ----
  float rinv[4];
  #pragma unroll
  for (int r=0; r<4; ++r) rinv[r] = 1.0f / __shfl(ell, g*4 + r);
  int b = bh >> 4, h = bh & 15;
  #pragma unroll
  for (int d=0; d<4; ++d)
    #pragma unroll
    for (int r=0; r<4; ++r){
      int s = q0 + wid*16 + g*4 + r;
      int col = h*64 + d*16 + lr;
      Xg[((size_t)b*SS + s)*DD + col] = f2bf(Xf[d][r] * rinv[r]);
    }
}

// ---------------- host ----------------
extern "C" void kernel_launch(void* const* d_in, const int* in_sizes, int n_in,
                              void* d_out, int out_size, void* d_ws, size_t ws_size,
                              hipStream_t stream){
  (void)in_sizes; (void)n_in; (void)out_size; (void)ws_size;
  const float* query = (const float*)d_in[0];
  const float* key   = (const float*)d_in[1];
  const float* value = (const float*)d_in[2];
  const float* fc_w  = (const float*)d_in[3];
  const float* Wq    = (const float*)d_in[4];
  const float* bq    = (const float*)d_in[5];
  const float* Wk    = (const float*)d_in[6];
  const float* bk    = (const float*)d_in[7];
  const float* Wv    = (const float*)d_in[8];
  const float* bv    = (const float*)d_in[9];
  const float* Wo    = (const float*)d_in[10];
  const float* bo    = (const float*)d_in[11];

  char* ws = (char*)d_ws;
  const size_t EL = (size_t)BB*SS*DD;          // 8388608 elems
  size_t off = 0;
  auto alloc = [&](size_t bytes){ size_t o = off; off += (bytes + 255) & ~(size_t)255; return o; };
  unsigned short* qb  = (unsigned short*)(ws + alloc(EL*2));
  unsigned short* kb  = (unsigned short*)(ws + alloc(EL*2));
  unsigned short* vb  = (unsigned short*)(ws + alloc(EL*2));
  unsigned short* Wqt = (unsigned short*)(ws + alloc((size_t)DD*DD*2));
  unsigned short* Wkt = (unsigned short*)(ws + alloc((size_t)DD*DD*2));
  unsigned short* Wvt = (unsigned short*)(ws + alloc((size_t)DD*DD*2));
  unsigned short* Wot = (unsigned short*)(ws + alloc((size_t)DD*DD*2));
  unsigned short* Qh  = (unsigned short*)(ws + alloc(EL*2));
  unsigned short* Kh  = (unsigned short*)(ws + alloc(EL*2));
  unsigned short* Vh  = (unsigned short*)(ws + alloc(EL*2));
  // Aliased buffers (keep peak ws use ~104MB):
  //   Vth aliases vb (vb dead after V-projection GEMM; transpose runs after it)
  //   Xh  aliases qb (qb dead after Q-projection GEMM; attn runs after it)
  unsigned short* Vth = vb;
  unsigned short* Xh  = qb;

  const int nbCvt = (int)(EL / 8 / 256);       // 4096
  cvt_bf16<<<nbCvt, 256, 0, stream>>>(query, qb);
  cvt_bf16<<<nbCvt, 256, 0, stream>>>(key,   kb);
  cvt_bf16<<<nbCvt, 256, 0, stream>>>(value, vb);
  prep_weights<<<dim3(1024, 4), 256, 0, stream>>>(fc_w, Wq, Wk, Wv, Wo, Wqt, Wkt, Wvt, Wot);

  gemm_bt<0><<<dim3(DD/128, MT/128), 256, 0, stream>>>(qb, Wqt, bq, Qh);
  gemm_bt<0><<<dim3(DD/128, MT/128), 256, 0, stream>>>(kb, Wkt, bk, Kh);
  gemm_bt<0><<<dim3(DD/128, MT/128), 256, 0, stream>>>(vb, Wvt, bv, Vh);

  transpose_v<<<dim3(SS/64, BB*HH), 256, 0, stream>>>(Vh, Vth);
  attn<<<dim3(SS/64, BB*HH), 256, 0, stream>>>(Qh, Kh, Vth, Xh);

  gemm_bt<1><<<dim3(DD/128, MT/128), 256, 0, stream>>>(Xh, Wot, bo, d_out);
}

// Round 3
// 402.103 us; speedup vs baseline: 1.2094x; 1.2094x over previous
//
#include <hip/hip_runtime.h>
#include <hip/hip_bf16.h>
#include <stdint.h>

#define BB 4
#define SS 2048
#define DD 1024
#define HH 16
#define DKK 64
#define MT (BB*SS)   // 8192
#define KK DD        // 1024

typedef __attribute__((ext_vector_type(8))) short bf16x8;
typedef __attribute__((ext_vector_type(4))) float f32x4;
typedef __attribute__((ext_vector_type(8))) unsigned short u16x8;

__device__ __forceinline__ unsigned short f2bf(float f){
  union { float f; unsigned u; } x; x.f = f;
  unsigned r = x.u + 0x7fffu + ((x.u >> 16) & 1u);   // RNE
  return (unsigned short)(r >> 16);
}

// fast float->bf16 (compiler lowers pairs to v_cvt_pk_bf16_f32; m240)
__device__ __forceinline__ short bfc(float x){
  return (short)__builtin_bit_cast(unsigned short, (__bf16)x);
}

__device__ __forceinline__ float ex2(float x){
#if __has_builtin(__builtin_amdgcn_exp2f)
  return __builtin_amdgcn_exp2f(x);
#else
  return exp2f(x);
#endif
}

__device__ __forceinline__ float fm3(float a, float b, float c){
  return fmaxf(fmaxf(a, b), c);    // clang fuses to v_max3_f32
}

__device__ __forceinline__ void gll16(const void* g, void* l){
  __builtin_amdgcn_global_load_lds(
      (const __attribute__((address_space(1))) void*)g,
      (__attribute__((address_space(3))) void*)l, 16, 0, 0);
}

// ---------------- fp32 -> bf16 convert (8 elems/thread) ----------------
__global__ __launch_bounds__(256) void cvt_bf16(const float* __restrict__ in,
                                                unsigned short* __restrict__ out){
  int i = blockIdx.x * 256 + threadIdx.x;
  const f32x4* p = (const f32x4*)in;
  f32x4 a = p[2*i], b = p[2*i+1];
  u16x8 o;
  #pragma unroll
  for (int j=0;j<4;j++){ o[j] = f2bf(a[j]); o[4+j] = f2bf(b[j]); }
  ((u16x8*)out)[i] = o;
}

// ---------------- weights: transpose to [N][K] bf16, fuse fc_w*Wq ----------------
__global__ __launch_bounds__(256) void prep_weights(
    const float* __restrict__ fc, const float* __restrict__ Wq,
    const float* __restrict__ Wk, const float* __restrict__ Wv,
    const float* __restrict__ Wo,
    unsigned short* __restrict__ Wqt, unsigned short* __restrict__ Wkt,
    unsigned short* __restrict__ Wvt, unsigned short* __restrict__ Wot){
  __shared__ float tile[32][33];
  int which = blockIdx.y;
  const float* src = which==0?Wq: which==1?Wk: which==2?Wv:Wo;
  unsigned short* dst = which==0?Wqt: which==1?Wkt: which==2?Wvt:Wot;
  int k0 = (blockIdx.x & 31)*32, n0 = (blockIdx.x >> 5)*32;
  int tid = threadIdx.x;
  #pragma unroll
  for (int i=0;i<4;i++){
    int e = tid + i*256; int r = e>>5, c = e&31;
    float v = src[(size_t)(k0+r)*DD + n0 + c];
    if (which==0) v *= fc[(size_t)(k0+r)*DD + n0 + c];
    tile[r][c] = v;
  }
  __syncthreads();
  #pragma unroll
  for (int i=0;i<4;i++){
    int e = tid + i*256; int r = e>>5, c = e&31;
    dst[(size_t)(n0+r)*DD + k0 + c] = f2bf(tile[c][r]);
  }
}

// ---------------- GEMM: C[M][N] = A[M][K](bf16) @ Bt[N][K]^T (bf16) + bias ----------------
// EPI=0: write bf16*(scale applied) in [B,H,S,DK] head layout.  EPI=1: fp32 [M][N].
// 1-D grid of 512 blocks, XCD-chunked swizzle: XCD x owns by in [8x,8x+8) so the
// 8 bx-tiles sharing one A-panel stay in one L2 (T1, bijective).
template<int EPI>
__global__ __launch_bounds__(256) void gemm_bt(
    const unsigned short* __restrict__ A,
    const unsigned short* __restrict__ Bt,
    const float* __restrict__ bias,
    float scale,
    void* __restrict__ Cout){
  __shared__ __align__(16) unsigned short Asb[2][128*32];
  __shared__ __align__(16) unsigned short Bsb[2][128*32];
  const int tid = threadIdx.x;
  const int lane = tid & 63, wid = tid >> 6;
  const int sidx = blockIdx.x;
  const int xcd = sidx & 7, jj = sidx >> 3;
  const int by = xcd*8 + (jj>>3), bx = jj & 7;      // grid 8(bx) x 64(by)
  const int m0 = by * 128, n0 = bx * 128;
  const int wm = wid >> 1, wn = wid & 1;
  const int g = lane >> 4, lr = lane & 15;

  f32x4 acc[4][4];
  #pragma unroll
  for (int i=0;i<4;i++)
    #pragma unroll
    for (int j=0;j<4;j++) acc[i][j] = (f32x4){0.f,0.f,0.f,0.f};

  const char* gaBase = (const char*)(A  + (size_t)m0 * KK);
  const char* gbBase = (const char*)(Bt + (size_t)n0 * KK);

  auto stage = [&](int buf, int kt){
    #pragma unroll
    for (int is=0; is<2; ++is){
      int t = is*4096 + wid*1024 + lane*16;   // tile byte (linear)
      int row = t >> 6, col = t & 63;         // 64B rows (BK=32 bf16)
      gll16(gaBase + (size_t)row*(KK*2) + (size_t)kt*64 + col,
            (char*)&Asb[buf][0] + is*4096 + wid*1024);
      gll16(gbBase + (size_t)row*(KK*2) + (size_t)kt*64 + col,
            (char*)&Bsb[buf][0] + is*4096 + wid*1024);
    }
  };

  stage(0, 0);
  __syncthreads();
  int cur = 0;
  for (int kt = 0; kt < KK/32; ++kt){
    if (kt + 1 < KK/32) stage(cur^1, kt+1);
    bf16x8 af[4], bfr[4];
    #pragma unroll
    for (int f=0; f<4; ++f){
      int ar = wm*64 + f*16 + lr;
      af[f]  = *(const bf16x8*)&Asb[cur][ar*32 + g*8];
      int br = wn*64 + f*16 + lr;
      bfr[f] = *(const bf16x8*)&Bsb[cur][br*32 + g*8];
    }
    #pragma unroll
    for (int i=0;i<4;i++)
      #pragma unroll
      for (int j=0;j<4;j++)
        acc[i][j] = __builtin_amdgcn_mfma_f32_16x16x32_bf16(af[i], bfr[j], acc[i][j], 0, 0, 0);
    __syncthreads();
    cur ^= 1;
  }

  #pragma unroll
  for (int j=0;j<4;j++){
    int n = n0 + wn*64 + j*16 + lr;
    float bv = bias[n];
    #pragma unroll
    for (int i=0;i<4;i++){
      int mbase = m0 + wm*64 + i*16 + g*4;
      #pragma unroll
      for (int r=0;r<4;r++){
        int m = mbase + r;
        float v = (acc[i][j][r] + bv) * scale;
        if (EPI == 0){
          int b = m >> 11, s = m & (SS-1);
          int h = n >> 6, dk = n & 63;
          ((unsigned short*)Cout)[(((size_t)(b*HH + h))*SS + s)*DKK + dk] = f2bf(v);
        } else {
          ((float*)Cout)[(size_t)m*DD + n] = v;
        }
      }
    }
  }
}

// ---------------- V [BH][S][64] -> Vt [BH][64][sigma(S)] ----------------
// sigma permutes s within each 64-tile (bit perm: out = b5,b3,b2,b4,b1,b0) so the
// attn PV B-fragment (8 k-slots of one lane group) is 16B-contiguous.
__global__ __launch_bounds__(256) void transpose_v(const unsigned short* __restrict__ V,
                                                   unsigned short* __restrict__ Vt){
  __shared__ unsigned short t[64][72];
  int bh = blockIdx.y; int s0 = blockIdx.x*64;
  const unsigned short* src = V + ((size_t)bh*SS + s0)*DKK;
  int tid = threadIdx.x;
  #pragma unroll
  for (int i=0;i<2;i++){
    int e = (tid + i*256)*8; int r = e>>6, c = e&63;
    int rp = (r & 35) | ((r & 12) << 1) | ((r & 16) >> 2);   // sigma(r)
    u16x8 v = *(const u16x8*)(src + (size_t)r*DKK + c);
    #pragma unroll
    for (int j=0;j<8;j++) t[c+j][rp] = v[j];
  }
  __syncthreads();
  unsigned short* dst = Vt + ((size_t)bh*DKK)*SS + s0;
  #pragma unroll
  for (int i=0;i<2;i++){
    int e = (tid + i*256)*8; int d = e>>6, c = e&63;
    u16x8 v = *(const u16x8*)(&t[d][c]);
    *(u16x8*)(dst + (size_t)d*SS + c) = v;
  }
}

// ---------------- flash attention ----------------
// Q pre-scaled by (1/sqrt(DK))*log2(e) in the Q projection. Vt sigma-permuted.
// Swapped QK^T -> per-lane P rows; log2-domain online softmax with defer-max
// (THR=8, T13); per-lane partial ell; P->bf16 via cvt_pk; single-b128 PV reads.
__global__ __launch_bounds__(256) void attn(
    const unsigned short* __restrict__ Qg,
    const unsigned short* __restrict__ Kg,
    const unsigned short* __restrict__ Vtg,
    unsigned short* __restrict__ Xg){
  __shared__ __align__(16) unsigned short Qs[64*64];
  __shared__ __align__(16) unsigned short Ks[2][64*64];
  __shared__ __align__(16) unsigned short Vs[2][64*64];
  const int tid = threadIdx.x;
  const int lane = tid & 63, wid = tid >> 6;
  const int g = lane >> 4, lr = lane & 15;
  const int bh = blockIdx.y;
  const int q0 = blockIdx.x * 64;

  const char* Qbase = (const char*)(Qg + ((size_t)bh*SS + q0)*DKK);
  const char* Kbase = (const char*)(Kg + (size_t)bh*SS*DKK);
  const char* Vbase = (const char*)(Vtg + (size_t)bh*DKK*SS);

  // ---- stage Q (8KB contiguous), source-swizzled (rule 21) ----
  #pragma unroll
  for (int is=0; is<2; ++is){
    int t = is*4096 + wid*1024 + lane*16;
    int row = t >> 7;
    int col = (t & 127) ^ ((row & 7) << 4);
    gll16(Qbase + row*128 + col, (char*)Qs + is*4096 + wid*1024);
  }

  auto stageK = [&](int buf, int it){
    const char* gk = Kbase + (size_t)it*8192;
    #pragma unroll
    for (int is=0; is<2; ++is){
      int t = is*4096 + wid*1024 + lane*16;
      int row = t >> 7;
      int col = (t & 127) ^ ((row & 7) << 4);
      gll16(gk + row*128 + col, (char*)&Ks[buf][0] + is*4096 + wid*1024);
    }
  };
  auto stageV = [&](int buf, int it){
    #pragma unroll
    for (int is=0; is<2; ++is){
      int t = is*4096 + wid*1024 + lane*16;
      int row = t >> 7;
      int col = (t & 127) ^ ((row & 7) << 4);
      gll16(Vbase + (size_t)row*(SS*2) + (size_t)it*128 + col,
            (char*)&Vs[buf][0] + is*4096 + wid*1024);
    }
  };

  stageK(0, 0); stageV(0, 0);
  __syncthreads();

  bf16x8 qf[2];
  {
    int qrow = wid*16 + lr;
    int sw = (qrow & 7) << 4;
    #pragma unroll
    for (int h2=0; h2<2; ++h2){
      int cb = (g*8 + h2*32) * 2;
      qf[h2] = *(const bf16x8*)((const char*)Qs + qrow*128 + (cb ^ sw));
    }
  }

  f32x4 Xf[4];
  #pragma unroll
  for (int d=0; d<4; ++d) Xf[d] = (f32x4){0.f,0.f,0.f,0.f};
  const f32x4 Zv = (f32x4){0.f,0.f,0.f,0.f};
  float m2 = -1e30f, ell = 0.f;           // ell: per-lane partial

  const int sw2 = (lr & 7) << 4;

  auto body = [&](int cb){
    const char* Kb = (const char*)&Ks[cb][0];
    const char* Vb = (const char*)&Vs[cb][0];
    // ---- S^T = K @ Q^T : lane holds S[kv = s*16 + g*4 + r][q = lr] ----
    f32x4 st[4];
    __builtin_amdgcn_s_setprio(1);
    #pragma unroll
    for (int s4=0; s4<4; ++s4){
      int rb = (s4*16 + lr) * 128;
      bf16x8 k0 = *(const bf16x8*)(Kb + rb + ((g*16     ) ^ sw2));
      bf16x8 k1 = *(const bf16x8*)(Kb + rb + ((g*16 + 64) ^ sw2));
      st[s4] = __builtin_amdgcn_mfma_f32_16x16x32_bf16(k0, qf[0], Zv,     0,0,0);
      st[s4] = __builtin_amdgcn_mfma_f32_16x16x32_bf16(k1, qf[1], st[s4], 0,0,0);
    }
    __builtin_amdgcn_s_setprio(0);

    // ---- online softmax, log2 domain, defer-max THR=8 ----
    float t0 = fm3(st[0][0], st[0][1], st[0][2]);
    float t1 = fm3(st[0][3], st[1][0], st[1][1]);
    float t2 = fm3(st[1][2], st[1][3], st[2][0]);
    float t3 = fm3(st[2][1], st[2][2], st[2][3]);
    float t4 = fm3(st[3][0], st[3][1], st[3][2]);
    float tmax = fm3(fm3(t0, t1, t2), fmaxf(t3, t4), st[3][3]);
    tmax = fmaxf(tmax, __shfl_xor(tmax, 16));
    tmax = fmaxf(tmax, __shfl_xor(tmax, 32));
    if (__any(tmax > m2 + 8.f)){
      float mn = fmaxf(m2, tmax);
      float sc = ex2(m2 - mn);
      m2 = mn;
      ell *= sc;
      #pragma unroll
      for (int r=0; r<4; ++r){
        float scr = __shfl(sc, g*4 + r);
        #pragma unroll
        for (int d=0; d<4; ++d) Xf[d][r] *= scr;
      }
    }
    float p[4][4];
    #pragma unroll
    for (int s4=0; s4<4; ++s4)
      #pragma unroll
      for (int r=0; r<4; ++r) p[s4][r] = ex2(st[s4][r] - m2);
    float ps0 = (p[0][0]+p[0][1]) + (p[0][2]+p[0][3]);
    float ps1 = (p[1][0]+p[1][1]) + (p[1][2]+p[1][3]);
    float ps2 = (p[2][0]+p[2][1]) + (p[2][2]+p[2][3]);
    float ps3 = (p[3][0]+p[3][1]) + (p[3][2]+p[3][3]);
    ell += (ps0+ps1) + (ps2+ps3);

    // ---- P -> bf16 A-fragments (k-slot map pi(g,j,mh) = 32mh+16(j>>2)+4g+(j&3)) ----
    bf16x8 pa0, pa1;
    #pragma unroll
    for (int j=0; j<8; ++j){
      pa0[j] = bfc(p[(j>>2)    ][j&3]);
      pa1[j] = bfc(p[2 + (j>>2)][j&3]);
    }

    // ---- X += P @ V  (sigma-permuted Vt: one b128 per (d,mh)) ----
    __builtin_amdgcn_s_setprio(1);
    #pragma unroll
    for (int d=0; d<4; ++d){
      int rb = (d*16 + lr) * 128;
      bf16x8 b0 = *(const bf16x8*)(Vb + rb + ((g*16     ) ^ sw2));
      bf16x8 b1 = *(const bf16x8*)(Vb + rb + ((g*16 + 64) ^ sw2));
      Xf[d] = __builtin_amdgcn_mfma_f32_16x16x32_bf16(pa0, b0, Xf[d], 0,0,0);
      Xf[d] = __builtin_amdgcn_mfma_f32_16x16x32_bf16(pa1, b1, Xf[d], 0,0,0);
    }
    __builtin_amdgcn_s_setprio(0);
  };

  for (int it = 0; it < SS/64; it += 2){
    if (it + 1 < SS/64){ stageK(1, it+1); stageV(1, it+1); }
    body(0);
    __syncthreads();
    if (it + 2 < SS/64){ stageK(0, it+2); stageV(0, it+2); }
    body(1);
    __syncthreads();
  }

  // ---- finalize: reduce partial ell over the 4 lane-groups, divide, store ----
  float elt = ell;
  elt += __shfl_xor(elt, 16);
  elt += __shfl_xor(elt, 32);
  float rinv[4];
  #pragma unroll
  for (int r=0; r<4; ++r) rinv[r] = 1.0f / __shfl(elt, g*4 + r);
  int b = bh >> 4, h = bh & 15;
  #pragma unroll
  for (int d=0; d<4; ++d)
    #pragma unroll
    for (int r=0; r<4; ++r){
      int s = q0 + wid*16 + g*4 + r;
      int col = h*64 + d*16 + lr;
      Xg[((size_t)b*SS + s)*DD + col] = f2bf(Xf[d][r] * rinv[r]);
    }
}

// ---------------- host ----------------
extern "C" void kernel_launch(void* const* d_in, const int* in_sizes, int n_in,
                              void* d_out, int out_size, void* d_ws, size_t ws_size,
                              hipStream_t stream){
  (void)in_sizes; (void)n_in; (void)out_size; (void)ws_size;
  const float* query = (const float*)d_in[0];
  const float* key   = (const float*)d_in[1];
  const float* value = (const float*)d_in[2];
  const float* fc_w  = (const float*)d_in[3];
  const float* Wq    = (const float*)d_in[4];
  const float* bq    = (const float*)d_in[5];
  const float* Wk    = (const float*)d_in[6];
  const float* bk    = (const float*)d_in[7];
  const float* Wv    = (const float*)d_in[8];
  const float* bv    = (const float*)d_in[9];
  const float* Wo    = (const float*)d_in[10];
  const float* bo    = (const float*)d_in[11];

  char* ws = (char*)d_ws;
  const size_t EL = (size_t)BB*SS*DD;          // 8388608 elems
  size_t off = 0;
  auto alloc = [&](size_t bytes){ size_t o = off; off += (bytes + 255) & ~(size_t)255; return o; };
  unsigned short* qb  = (unsigned short*)(ws + alloc(EL*2));
  unsigned short* kb  = (unsigned short*)(ws + alloc(EL*2));
  unsigned short* vb  = (unsigned short*)(ws + alloc(EL*2));
  unsigned short* Wqt = (unsigned short*)(ws + alloc((size_t)DD*DD*2));
  unsigned short* Wkt = (unsigned short*)(ws + alloc((size_t)DD*DD*2));
  unsigned short* Wvt = (unsigned short*)(ws + alloc((size_t)DD*DD*2));
  unsigned short* Wot = (unsigned short*)(ws + alloc((size_t)DD*DD*2));
  unsigned short* Qh  = (unsigned short*)(ws + alloc(EL*2));
  unsigned short* Kh  = (unsigned short*)(ws + alloc(EL*2));
  unsigned short* Vh  = (unsigned short*)(ws + alloc(EL*2));
  // Aliased buffers:
  //   Vth aliases vb (vb dead after V-projection GEMM; transpose runs after it)
  //   Xh  aliases qb (qb dead after Q-projection GEMM; attn runs after it)
  unsigned short* Vth = vb;
  unsigned short* Xh  = qb;

  const float SC2 = 0.18033688011112042f;      // (1/sqrt(64)) * log2(e), folded into Q

  const int nbCvt = (int)(EL / 8 / 256);       // 4096
  cvt_bf16<<<nbCvt, 256, 0, stream>>>(query, qb);
  cvt_bf16<<<nbCvt, 256, 0, stream>>>(key,   kb);
  cvt_bf16<<<nbCvt, 256, 0, stream>>>(value, vb);
  prep_weights<<<dim3(1024, 4), 256, 0, stream>>>(fc_w, Wq, Wk, Wv, Wo, Wqt, Wkt, Wvt, Wot);

  gemm_bt<0><<<512, 256, 0, stream>>>(qb, Wqt, bq, SC2, Qh);
  gemm_bt<0><<<512, 256, 0, stream>>>(kb, Wkt, bk, 1.0f, Kh);
  gemm_bt<0><<<512, 256, 0, stream>>>(vb, Wvt, bv, 1.0f, Vh);

  transpose_v<<<dim3(SS/64, BB*HH), 256, 0, stream>>>(Vh, Vth);
  attn<<<dim3(SS/64, BB*HH), 256, 0, stream>>>(Qh, Kh, Vth, Xh);

  gemm_bt<1><<<512, 256, 0, stream>>>(Xh, Wot, bo, 1.0f, d_out);
}

// Round 4
// 379.589 us; speedup vs baseline: 1.2812x; 1.0593x over previous
//
#include <hip/hip_runtime.h>
#include <hip/hip_bf16.h>
#include <stdint.h>

#define BB 4
#define SS 2048
#define DD 1024
#define HH 16
#define DKK 64
#define MT (BB*SS)   // 8192
#define KK DD        // 1024

typedef __attribute__((ext_vector_type(8))) short bf16x8;
typedef __attribute__((ext_vector_type(4))) float f32x4;
typedef __attribute__((ext_vector_type(8))) unsigned short u16x8;

__device__ __forceinline__ unsigned short f2bf(float f){
  union { float f; unsigned u; } x; x.f = f;
  unsigned r = x.u + 0x7fffu + ((x.u >> 16) & 1u);   // RNE
  return (unsigned short)(r >> 16);
}

// fast float->bf16 (compiler lowers pairs to v_cvt_pk_bf16_f32; m240)
__device__ __forceinline__ short bfc(float x){
  return (short)__builtin_bit_cast(unsigned short, (__bf16)x);
}

__device__ __forceinline__ float ex2(float x){
#if __has_builtin(__builtin_amdgcn_exp2f)
  return __builtin_amdgcn_exp2f(x);
#else
  return exp2f(x);
#endif
}

__device__ __forceinline__ float fm3(float a, float b, float c){
  return fmaxf(fmaxf(a, b), c);    // clang fuses to v_max3_f32
}

__device__ __forceinline__ void gll16(const void* g, void* l){
  __builtin_amdgcn_global_load_lds(
      (const __attribute__((address_space(1))) void*)g,
      (__attribute__((address_space(3))) void*)l, 16, 0, 0);
}

// ---------------- fp32 -> bf16 convert (8 elems/thread) ----------------
__global__ __launch_bounds__(256) void cvt_bf16(const float* __restrict__ in,
                                                unsigned short* __restrict__ out){
  int i = blockIdx.x * 256 + threadIdx.x;
  const f32x4* p = (const f32x4*)in;
  f32x4 a = p[2*i], b = p[2*i+1];
  u16x8 o;
  #pragma unroll
  for (int j=0;j<4;j++){ o[j] = f2bf(a[j]); o[4+j] = f2bf(b[j]); }
  ((u16x8*)out)[i] = o;
}

// ---------------- weights: transpose to [N][K] bf16, fuse fc_w*Wq ----------------
__global__ __launch_bounds__(256) void prep_weights(
    const float* __restrict__ fc, const float* __restrict__ Wq,
    const float* __restrict__ Wk, const float* __restrict__ Wv,
    const float* __restrict__ Wo,
    unsigned short* __restrict__ Wqt, unsigned short* __restrict__ Wkt,
    unsigned short* __restrict__ Wvt, unsigned short* __restrict__ Wot){
  __shared__ float tile[32][33];
  int which = blockIdx.y;
  const float* src = which==0?Wq: which==1?Wk: which==2?Wv:Wo;
  unsigned short* dst = which==0?Wqt: which==1?Wkt: which==2?Wvt:Wot;
  int k0 = (blockIdx.x & 31)*32, n0 = (blockIdx.x >> 5)*32;
  int tid = threadIdx.x;
  #pragma unroll
  for (int i=0;i<4;i++){
    int e = tid + i*256; int r = e>>5, c = e&31;
    float v = src[(size_t)(k0+r)*DD + n0 + c];
    if (which==0) v *= fc[(size_t)(k0+r)*DD + n0 + c];
    tile[r][c] = v;
  }
  __syncthreads();
  #pragma unroll
  for (int i=0;i<4;i++){
    int e = tid + i*256; int r = e>>5, c = e&31;
    dst[(size_t)(n0+r)*DD + k0 + c] = f2bf(tile[c][r]);
  }
}

// ================= GEMM body (m97 structure, 128x128 tile, BK=32) ==============
// EPI=0: bf16*(scale) in [B,H,S,DK] head layout.  EPI=1: fp32 [M][N].
#define GEMM_BODY(EPI, A, Bt, bias, scale, Cout, m0, n0)                          \
  {                                                                               \
  const int tid = threadIdx.x;                                                    \
  const int lane = tid & 63, wid = tid >> 6;                                      \
  const int wm = wid >> 1, wn = wid & 1;                                          \
  const int g = lane >> 4, lr = lane & 15;                                        \
  f32x4 acc[4][4];                                                                \
  _Pragma("unroll")                                                               \
  for (int i=0;i<4;i++)                                                           \
    _Pragma("unroll")                                                             \
    for (int j=0;j<4;j++) acc[i][j] = (f32x4){0.f,0.f,0.f,0.f};                   \
  const char* gaBase = (const char*)((A)  + (size_t)(m0) * KK);                   \
  const char* gbBase = (const char*)((Bt) + (size_t)(n0) * KK);                   \
  auto stage = [&](int buf, int kt){                                              \
    _Pragma("unroll")                                                             \
    for (int is=0; is<2; ++is){                                                   \
      int t = is*4096 + wid*1024 + lane*16;                                       \
      int row = t >> 6, col = t & 63;                                             \
      gll16(gaBase + (size_t)row*(KK*2) + (size_t)kt*64 + col,                    \
            (char*)&Asb[buf][0] + is*4096 + wid*1024);                            \
      gll16(gbBase + (size_t)row*(KK*2) + (size_t)kt*64 + col,                    \
            (char*)&Bsb[buf][0] + is*4096 + wid*1024);                            \
    }                                                                             \
  };                                                                              \
  stage(0, 0);                                                                    \
  __syncthreads();                                                                \
  int cur = 0;                                                                    \
  for (int kt = 0; kt < KK/32; ++kt){                                             \
    if (kt + 1 < KK/32) stage(cur^1, kt+1);                                       \
    bf16x8 af[4], bfr[4];                                                         \
    _Pragma("unroll")                                                             \
    for (int f=0; f<4; ++f){                                                      \
      int ar = wm*64 + f*16 + lr;                                                 \
      af[f]  = *(const bf16x8*)&Asb[cur][ar*32 + g*8];                            \
      int br = wn*64 + f*16 + lr;                                                 \
      bfr[f] = *(const bf16x8*)&Bsb[cur][br*32 + g*8];                            \
    }                                                                             \
    _Pragma("unroll")                                                             \
    for (int i=0;i<4;i++)                                                         \
      _Pragma("unroll")                                                           \
      for (int j=0;j<4;j++)                                                       \
        acc[i][j] = __builtin_amdgcn_mfma_f32_16x16x32_bf16(af[i], bfr[j], acc[i][j], 0, 0, 0); \
    __syncthreads();                                                              \
    cur ^= 1;                                                                     \
  }                                                                               \
  _Pragma("unroll")                                                               \
  for (int j=0;j<4;j++){                                                          \
    int n = (n0) + wn*64 + j*16 + lr;                                             \
    float bv = (bias)[n];                                                         \
    _Pragma("unroll")                                                             \
    for (int i=0;i<4;i++){                                                        \
      int mbase = (m0) + wm*64 + i*16 + g*4;                                      \
      _Pragma("unroll")                                                           \
      for (int r=0;r<4;r++){                                                      \
        int m = mbase + r;                                                        \
        float v = (acc[i][j][r] + bv) * (scale);                                  \
        if (EPI == 0){                                                            \
          int b = m >> 11, s = m & (SS-1);                                        \
          int h = n >> 6, dk = n & 63;                                            \
          ((unsigned short*)(Cout))[(((size_t)(b*HH + h))*SS + s)*DKK + dk] = f2bf(v); \
        } else {                                                                  \
          ((float*)(Cout))[(size_t)m*DD + n] = v;                                 \
        }                                                                         \
      }                                                                           \
    }                                                                             \
  }                                                                               \
  }

// Merged Q/K/V projection GEMM: 1536 blocks (3 x 512), XCD-chunked per matrix.
__global__ __launch_bounds__(256) void gemm_qkv(
    const unsigned short* __restrict__ Aq, const unsigned short* __restrict__ Ak,
    const unsigned short* __restrict__ Av,
    const unsigned short* __restrict__ Wq, const unsigned short* __restrict__ Wk,
    const unsigned short* __restrict__ Wv,
    const float* __restrict__ bq, const float* __restrict__ bk,
    const float* __restrict__ bv, float qscale,
    unsigned short* __restrict__ Qo, unsigned short* __restrict__ Ko,
    unsigned short* __restrict__ Vo){
  __shared__ __align__(16) unsigned short Asb[2][128*32];
  __shared__ __align__(16) unsigned short Bsb[2][128*32];
  const int u = blockIdx.x;
  const int which = u % 3, v = u / 3;
  const int xcd = v & 7, jj = v >> 3;
  const int by = xcd*8 + (jj>>3), bx = jj & 7;
  const int m0 = by * 128, n0 = bx * 128;
  const unsigned short* A  = which==0 ? Aq : which==1 ? Ak : Av;
  const unsigned short* Bt = which==0 ? Wq : which==1 ? Wk : Wv;
  const float* bias        = which==0 ? bq : which==1 ? bk : bv;
  unsigned short* C        = which==0 ? Qo : which==1 ? Ko : Vo;
  float scale = which==0 ? qscale : 1.0f;
  GEMM_BODY(0, A, Bt, bias, scale, C, m0, n0)
}

// Output projection GEMM (fp32 out), 512 blocks.
__global__ __launch_bounds__(256) void gemm_o(
    const unsigned short* __restrict__ A, const unsigned short* __restrict__ Bt,
    const float* __restrict__ bias, float* __restrict__ Cout){
  __shared__ __align__(16) unsigned short Asb[2][128*32];
  __shared__ __align__(16) unsigned short Bsb[2][128*32];
  const int sidx = blockIdx.x;
  const int xcd = sidx & 7, jj = sidx >> 3;
  const int by = xcd*8 + (jj>>3), bx = jj & 7;
  const int m0 = by * 128, n0 = bx * 128;
  GEMM_BODY(1, A, Bt, bias, 1.0f, Cout, m0, n0)
}

// ---------------- V [BH][S][64] -> Vt [BH][64][sigma(S)] ----------------
// sigma permutes s within each 64-tile (bit perm: out = b5,b3,b2,b4,b1,b0) so the
// attn PV B-fragment (8 k-slots of one lane group) is 16B-contiguous.
__global__ __launch_bounds__(256) void transpose_v(const unsigned short* __restrict__ V,
                                                   unsigned short* __restrict__ Vt){
  __shared__ unsigned short t[64][72];
  int bh = blockIdx.y; int s0 = blockIdx.x*64;
  const unsigned short* src = V + ((size_t)bh*SS + s0)*DKK;
  int tid = threadIdx.x;
  #pragma unroll
  for (int i=0;i<2;i++){
    int e = (tid + i*256)*8; int r = e>>6, c = e&63;
    int rp = (r & 35) | ((r & 12) << 1) | ((r & 16) >> 2);   // sigma(r)
    u16x8 v = *(const u16x8*)(src + (size_t)r*DKK + c);
    #pragma unroll
    for (int j=0;j<8;j++) t[c+j][rp] = v[j];
  }
  __syncthreads();
  unsigned short* dst = Vt + ((size_t)bh*DKK)*SS + s0;
  #pragma unroll
  for (int i=0;i<2;i++){
    int e = (tid + i*256)*8; int d = e>>6, c = e&63;
    u16x8 v = *(const u16x8*)(&t[d][c]);
    *(u16x8*)(dst + (size_t)d*SS + c) = v;
  }
}

// ---------------- flash attention (128 q/block, 32 q/wave) ----------------
// Q pre-scaled by (1/sqrt(DK))*log2(e). Vt sigma-permuted. Swapped QK^T ->
// per-lane P rows; log2-domain online softmax w/ defer-max (T13); Q direct
// from global (no LDS); K/V double-buffered LDS, XOR-swizzled (rule 21).
// Two q-subtiles (u=0,1) per wave share every K/V LDS read -> LDS traffic
// per MFMA halved vs QBLK=64.
__global__ __launch_bounds__(256) void attn(
    const unsigned short* __restrict__ Qg,
    const unsigned short* __restrict__ Kg,
    const unsigned short* __restrict__ Vtg,
    unsigned short* __restrict__ Xg){
  __shared__ __align__(16) unsigned short Ks[2][64*64];
  __shared__ __align__(16) unsigned short Vs[2][64*64];
  const int tid = threadIdx.x;
  const int lane = tid & 63, wid = tid >> 6;
  const int g = lane >> 4, lr = lane & 15;
  const int bh = blockIdx.y;
  const int q0 = blockIdx.x * 128;

  const unsigned short* Qrow = Qg + ((size_t)bh*SS + q0)*DKK;
  const char* Kbase = (const char*)(Kg + (size_t)bh*SS*DKK);
  const char* Vbase = (const char*)(Vtg + (size_t)bh*DKK*SS);

  auto stageK = [&](int buf, int it){
    const char* gk = Kbase + (size_t)it*8192;
    #pragma unroll
    for (int is=0; is<2; ++is){
      int t = is*4096 + wid*1024 + lane*16;
      int row = t >> 7;
      int col = (t & 127) ^ ((row & 7) << 4);
      gll16(gk + row*128 + col, (char*)&Ks[buf][0] + is*4096 + wid*1024);
    }
  };
  auto stageV = [&](int buf, int it){
    #pragma unroll
    for (int is=0; is<2; ++is){
      int t = is*4096 + wid*1024 + lane*16;
      int row = t >> 7;
      int col = (t & 127) ^ ((row & 7) << 4);
      gll16(Vbase + (size_t)row*(SS*2) + (size_t)it*128 + col,
            (char*)&Vs[buf][0] + is*4096 + wid*1024);
    }
  };

  stageK(0, 0); stageV(0, 0);

  // Q fragments direct from global (block reads Q tile exactly once)
  bf16x8 qf[2][2];
  #pragma unroll
  for (int u=0; u<2; ++u){
    int qrow = wid*32 + u*16 + lr;
    #pragma unroll
    for (int h2=0; h2<2; ++h2)
      qf[u][h2] = *(const bf16x8*)(Qrow + (size_t)qrow*DKK + g*8 + h2*32);
  }

  f32x4 Xf[2][4];
  #pragma unroll
  for (int u=0; u<2; ++u)
    #pragma unroll
    for (int d=0; d<4; ++d) Xf[u][d] = (f32x4){0.f,0.f,0.f,0.f};
  const f32x4 Zv = (f32x4){0.f,0.f,0.f,0.f};
  float m2[2] = {-1e30f, -1e30f}, ell[2] = {0.f, 0.f};
  const int sw2 = (lr & 7) << 4;

  __syncthreads();

  auto body = [&](int cbuf){
    const char* Kb = (const char*)&Ks[cbuf][0];
    const char* Vb = (const char*)&Vs[cbuf][0];
    // ---- S^T = K @ Q^T : lane holds S[kv = s4*16 + g*4 + r][q = u*16 + lr] ----
    f32x4 st[4][2];
    __builtin_amdgcn_s_setprio(1);
    #pragma unroll
    for (int s4=0; s4<4; ++s4){
      int rb = (s4*16 + lr) * 128;
      bf16x8 k0 = *(const bf16x8*)(Kb + rb + ((g*16     ) ^ sw2));
      bf16x8 k1 = *(const bf16x8*)(Kb + rb + ((g*16 + 64) ^ sw2));
      st[s4][0] = __builtin_amdgcn_mfma_f32_16x16x32_bf16(k0, qf[0][0], Zv,        0,0,0);
      st[s4][0] = __builtin_amdgcn_mfma_f32_16x16x32_bf16(k1, qf[0][1], st[s4][0], 0,0,0);
      st[s4][1] = __builtin_amdgcn_mfma_f32_16x16x32_bf16(k0, qf[1][0], Zv,        0,0,0);
      st[s4][1] = __builtin_amdgcn_mfma_f32_16x16x32_bf16(k1, qf[1][1], st[s4][1], 0,0,0);
    }
    __builtin_amdgcn_s_setprio(0);

    bf16x8 pa[2][2];
    #pragma unroll
    for (int u=0; u<2; ++u){
      // online softmax, log2 domain, defer-max THR=8
      float t0 = fm3(st[0][u][0], st[0][u][1], st[0][u][2]);
      float t1 = fm3(st[0][u][3], st[1][u][0], st[1][u][1]);
      float t2 = fm3(st[1][u][2], st[1][u][3], st[2][u][0]);
      float t3 = fm3(st[2][u][1], st[2][u][2], st[2][u][3]);
      float t4 = fm3(st[3][u][0], st[3][u][1], st[3][u][2]);
      float tmax = fm3(fm3(t0, t1, t2), fmaxf(t3, t4), st[3][u][3]);
      tmax = fmaxf(tmax, __shfl_xor(tmax, 16));
      tmax = fmaxf(tmax, __shfl_xor(tmax, 32));
      if (__any(tmax > m2[u] + 8.f)){
        float mn = fmaxf(m2[u], tmax);
        float sc = ex2(m2[u] - mn);
        m2[u] = mn;
        ell[u] *= sc;
        #pragma unroll
        for (int r=0; r<4; ++r){
          float scr = __shfl(sc, g*4 + r);
          #pragma unroll
          for (int d=0; d<4; ++d) Xf[u][d][r] *= scr;
        }
      }
      #pragma unroll
      for (int s4=0; s4<4; ++s4)
        #pragma unroll
        for (int r=0; r<4; ++r) st[s4][u][r] = ex2(st[s4][u][r] - m2[u]);
      float ps0 = (st[0][u][0]+st[0][u][1]) + (st[0][u][2]+st[0][u][3]);
      float ps1 = (st[1][u][0]+st[1][u][1]) + (st[1][u][2]+st[1][u][3]);
      float ps2 = (st[2][u][0]+st[2][u][1]) + (st[2][u][2]+st[2][u][3]);
      float ps3 = (st[3][u][0]+st[3][u][1]) + (st[3][u][2]+st[3][u][3]);
      ell[u] += (ps0+ps1) + (ps2+ps3);
      // P -> bf16 A-fragments (k-slot map pi(g,j,mh) = 32mh+16(j>>2)+4g+(j&3))
      #pragma unroll
      for (int j=0; j<8; ++j){
        pa[u][0][j] = bfc(st[(j>>2)    ][u][j&3]);
        pa[u][1][j] = bfc(st[2 + (j>>2)][u][j&3]);
      }
    }

    // ---- X += P @ V  (sigma-permuted Vt; b0/b1 shared by both q-subtiles) ----
    __builtin_amdgcn_s_setprio(1);
    #pragma unroll
    for (int d=0; d<4; ++d){
      int rb = (d*16 + lr) * 128;
      bf16x8 b0 = *(const bf16x8*)(Vb + rb + ((g*16     ) ^ sw2));
      bf16x8 b1 = *(const bf16x8*)(Vb + rb + ((g*16 + 64) ^ sw2));
      Xf[0][d] = __builtin_amdgcn_mfma_f32_16x16x32_bf16(pa[0][0], b0, Xf[0][d], 0,0,0);
      Xf[0][d] = __builtin_amdgcn_mfma_f32_16x16x32_bf16(pa[0][1], b1, Xf[0][d], 0,0,0);
      Xf[1][d] = __builtin_amdgcn_mfma_f32_16x16x32_bf16(pa[1][0], b0, Xf[1][d], 0,0,0);
      Xf[1][d] = __builtin_amdgcn_mfma_f32_16x16x32_bf16(pa[1][1], b1, Xf[1][d], 0,0,0);
    }
    __builtin_amdgcn_s_setprio(0);
  };

  for (int it = 0; it < SS/64; it += 2){
    if (it + 1 < SS/64){ stageK(1, it+1); stageV(1, it+1); }
    body(0);
    __syncthreads();
    if (it + 2 < SS/64){ stageK(0, it+2); stageV(0, it+2); }
    body(1);
    __syncthreads();
  }

  // ---- finalize: reduce partial ell over lane-groups, divide, store ----
  int b = bh >> 4, h = bh & 15;
  #pragma unroll
  for (int u=0; u<2; ++u){
    float elt = ell[u];
    elt += __shfl_xor(elt, 16);
    elt += __shfl_xor(elt, 32);
    float rinv[4];
    #pragma unroll
    for (int r=0; r<4; ++r) rinv[r] = 1.0f / __shfl(elt, g*4 + r);
    #pragma unroll
    for (int d=0; d<4; ++d)
      #pragma unroll
      for (int r=0; r<4; ++r){
        int s = q0 + wid*32 + u*16 + g*4 + r;
        int col = h*64 + d*16 + lr;
        Xg[((size_t)b*SS + s)*DD + col] = f2bf(Xf[u][d][r] * rinv[r]);
      }
  }
}

// ---------------- host ----------------
extern "C" void kernel_launch(void* const* d_in, const int* in_sizes, int n_in,
                              void* d_out, int out_size, void* d_ws, size_t ws_size,
                              hipStream_t stream){
  (void)in_sizes; (void)n_in; (void)out_size; (void)ws_size;
  const float* query = (const float*)d_in[0];
  const float* key   = (const float*)d_in[1];
  const float* value = (const float*)d_in[2];
  const float* fc_w  = (const float*)d_in[3];
  const float* Wq    = (const float*)d_in[4];
  const float* bq    = (const float*)d_in[5];
  const float* Wk    = (const float*)d_in[6];
  const float* bk    = (const float*)d_in[7];
  const float* Wv    = (const float*)d_in[8];
  const float* bv    = (const float*)d_in[9];
  const float* Wo    = (const float*)d_in[10];
  const float* bo    = (const float*)d_in[11];

  char* ws = (char*)d_ws;
  const size_t EL = (size_t)BB*SS*DD;          // 8388608 elems
  size_t off = 0;
  auto alloc = [&](size_t bytes){ size_t o = off; off += (bytes + 255) & ~(size_t)255; return o; };
  unsigned short* qb  = (unsigned short*)(ws + alloc(EL*2));
  unsigned short* kb  = (unsigned short*)(ws + alloc(EL*2));
  unsigned short* vb  = (unsigned short*)(ws + alloc(EL*2));
  unsigned short* Wqt = (unsigned short*)(ws + alloc((size_t)DD*DD*2));
  unsigned short* Wkt = (unsigned short*)(ws + alloc((size_t)DD*DD*2));
  unsigned short* Wvt = (unsigned short*)(ws + alloc((size_t)DD*DD*2));
  unsigned short* Wot = (unsigned short*)(ws + alloc((size_t)DD*DD*2));
  unsigned short* Qh  = (unsigned short*)(ws + alloc(EL*2));
  unsigned short* Kh  = (unsigned short*)(ws + alloc(EL*2));
  unsigned short* Vh  = (unsigned short*)(ws + alloc(EL*2));
  // Aliased buffers:
  //   Vth aliases vb (vb dead after V-projection GEMM; transpose runs after it)
  //   Xh  aliases qb (qb dead after Q-projection GEMM; attn runs after it)
  unsigned short* Vth = vb;
  unsigned short* Xh  = qb;

  const float SC2 = 0.18033688011112042f;      // (1/sqrt(64)) * log2(e), folded into Q

  const int nbCvt = (int)(EL / 8 / 256);       // 4096
  cvt_bf16<<<nbCvt, 256, 0, stream>>>(query, qb);
  cvt_bf16<<<nbCvt, 256, 0, stream>>>(key,   kb);
  cvt_bf16<<<nbCvt, 256, 0, stream>>>(value, vb);
  prep_weights<<<dim3(1024, 4), 256, 0, stream>>>(fc_w, Wq, Wk, Wv, Wo, Wqt, Wkt, Wvt, Wot);

  gemm_qkv<<<1536, 256, 0, stream>>>(qb, kb, vb, Wqt, Wkt, Wvt, bq, bk, bv, SC2,
                                     Qh, Kh, Vh);

  transpose_v<<<dim3(SS/64, BB*HH), 256, 0, stream>>>(Vh, Vth);
  attn<<<dim3(SS/128, BB*HH), 256, 0, stream>>>(Qh, Kh, Vth, Xh);

  gemm_o<<<512, 256, 0, stream>>>(Xh, Wot, bo, (float*)d_out);
}